// Round 1
// baseline (1151.828 us; speedup 1.0000x reference)
//
#include <hip/hip_runtime.h>
#include <cstdint>
#include <cstddef>

#define NN 16384
#define FF 64

typedef _Float16 f16;
typedef _Float16 f16x4 __attribute__((ext_vector_type(4)));
typedef float f32x4 __attribute__((ext_vector_type(4)));

// async global->LDS, 16B per lane. LDS dest = wave-uniform base + lane*16.
__device__ __forceinline__ void async_copy16(void* lds, const void* gsrc) {
  auto l = reinterpret_cast<__attribute__((address_space(3))) uint32_t*>(
      reinterpret_cast<uintptr_t>(lds));
  auto g = reinterpret_cast<const __attribute__((address_space(1))) uint32_t*>(
      reinterpret_cast<uintptr_t>(gsrc));
  __builtin_amdgcn_global_load_lds(g, l, 16, 0, 0);
}

// ---------------------------------------------------------------------------
// Kernel 0: S1t[f][i] = (x @ W1)[i][f] as f16  (transposed for B-frag loads)
// ---------------------------------------------------------------------------
__global__ __launch_bounds__(256, 1)
void xw_kernel(const float* __restrict__ x, const float* __restrict__ W1,
               f16* __restrict__ S1t) {
  __shared__ __align__(16) char smem[24576];
  f16* X  = (f16*)smem;            // [64 rows][64 k]
  f16* Wt = (f16*)(smem + 8192);   // [64 n][64 k]  (= W1 transposed)
  f16* T  = (f16*)(smem + 16384);  // [64 col][64 row]
  const int tid = threadIdx.x;
  const int wv = tid >> 6, lane = tid & 63;
  const int lr = lane & 15, lg = lane >> 4;
  const int m0 = blockIdx.x * 64;

  {
    int row = tid >> 2, c0 = (tid & 3) * 16;
    const float* xr = x + (size_t)(m0 + row) * FF + c0;
#pragma unroll
    for (int j = 0; j < 4; ++j) {
      f32x4 v = *(const f32x4*)(xr + 4 * j);
#pragma unroll
      for (int i = 0; i < 4; ++i) X[row * 64 + c0 + 4 * j + i] = (f16)v[i];
    }
    const float* wr = W1 + (size_t)row * FF + c0;   // row=k, c0=n0
#pragma unroll
    for (int i = 0; i < 16; ++i) Wt[(c0 + i) * 64 + row] = (f16)wr[i];
  }
  __syncthreads();

  f32x4 acc[4] = {};
#pragma unroll
  for (int kk = 0; kk < 4; ++kk) {
    f16x4 a = *(const f16x4*)(X + (16 * wv + lr) * 64 + kk * 16 + 4 * lg);
#pragma unroll
    for (int nt = 0; nt < 4; ++nt) {
      f16x4 b = *(const f16x4*)(Wt + (nt * 16 + lr) * 64 + kk * 16 + 4 * lg);
      acc[nt] = __builtin_amdgcn_mfma_f32_16x16x16f16(a, b, acc[nt], 0, 0, 0);
    }
  }
  __syncthreads();
#pragma unroll
  for (int nt = 0; nt < 4; ++nt)
#pragma unroll
    for (int r = 0; r < 4; ++r)
      T[(nt * 16 + lr) * 64 + 16 * wv + 4 * lg + r] = (f16)acc[nt][r];
  __syncthreads();
  {
    int col = tid >> 2, r0 = (tid & 3) * 16;
#pragma unroll
    for (int h = 0; h < 2; ++h)
      *(f32x4*)(S1t + (size_t)col * NN + m0 + r0 + 8 * h) =
          *(const f32x4*)(T + col * 64 + r0 + 8 * h);
  }
}

// ---------------------------------------------------------------------------
// Main pass: C = adj @ S (+bias, [relu, @W2 -> S2t] | [*w -> out])
// 256 blocks x 256 threads (4 waves), BM=64, BK=64, double-buffered LDS.
// PASS==0: layer-1 aggregation + fused feature transform -> S2t (f16, transposed)
// PASS==1: layer-2 aggregation + bias + *w -> out (fp32), plus w copy
// ---------------------------------------------------------------------------
template <int PASS>
__global__ __launch_bounds__(256, 1)
void adj_pass(const float* __restrict__ adj, const f16* __restrict__ Bt,
              const float* __restrict__ bias, const float* __restrict__ W2,
              const float* __restrict__ wvec, f16* __restrict__ S2t,
              float* __restrict__ out, float* __restrict__ wout) {
  __shared__ __align__(16) char smem[49152];
  float* Ab = (float*)smem;            // [2][64][64] fp32  (32 KB)
  f16*   Bb = (f16*)(smem + 32768);    // [2][64 n][64 k] f16 (16 KB)
  const int tid = threadIdx.x;
  const int wv = tid >> 6;
  const int lane = tid & 63;
  const int lr = lane & 15, lg = lane >> 4;
  const int m0 = blockIdx.x * 64;

  f32x4 acc[4] = {};

#define STAGE(kb_, buf_)                                                        \
  do {                                                                          \
    float* Abase = Ab + (buf_) * 4096;                                          \
    f16*   Bbase = Bb + (buf_) * 4096;                                          \
    _Pragma("unroll")                                                           \
    for (int j = 0; j < 4; ++j) {                                               \
      int rb = 16 * wv + 4 * j;                                                 \
      const float* g = adj + (size_t)(m0 + rb + (lane >> 4)) * NN + (kb_) +     \
                       (lane & 15) * 4;                                         \
      async_copy16(Abase + rb * 64, g);                                         \
    }                                                                           \
    _Pragma("unroll")                                                           \
    for (int j = 0; j < 2; ++j) {                                               \
      int nb = 16 * wv + 8 * j;                                                 \
      const f16* g = Bt + (size_t)(nb + (lane >> 3)) * NN + (kb_) +             \
                     (lane & 7) * 8;                                            \
      async_copy16(Bbase + nb * 64, g);                                         \
    }                                                                           \
  } while (0)

#define COMPUTE(buf_)                                                           \
  do {                                                                          \
    const float* Abase = Ab + (buf_) * 4096;                                    \
    const f16*   Bbase = Bb + (buf_) * 4096;                                    \
    _Pragma("unroll")                                                           \
    for (int kk = 0; kk < 4; ++kk) {                                            \
      f32x4 av = *(const f32x4*)(Abase + (16 * wv + lr) * 64 + kk * 16 + 4 * lg); \
      f16x4 a = {(f16)av[0], (f16)av[1], (f16)av[2], (f16)av[3]};               \
      _Pragma("unroll")                                                         \
      for (int nt = 0; nt < 4; ++nt) {                                          \
        f16x4 b = *(const f16x4*)(Bbase + (nt * 16 + lr) * 64 + kk * 16 + 4 * lg); \
        acc[nt] = __builtin_amdgcn_mfma_f32_16x16x16f16(a, b, acc[nt], 0, 0, 0); \
      }                                                                         \
    }                                                                           \
  } while (0)

  STAGE(0, 0);
  asm volatile("s_waitcnt vmcnt(0)" ::: "memory");
  __builtin_amdgcn_s_barrier();
  int cur = 0;
  for (int t = 0; t < NN / 64; ++t) {
    if (t + 1 < NN / 64) STAGE((t + 1) * 64, cur ^ 1);
    COMPUTE(cur);
    asm volatile("s_waitcnt vmcnt(0)" ::: "memory");
    __builtin_amdgcn_s_barrier();
    cur ^= 1;
  }
#undef STAGE
#undef COMPUTE

  if constexpr (PASS == 0) {
    // h = acc + b1; relu; F (f16) -> second MFMA vs W2 -> transpose-write S2t
    f16* F  = (f16*)smem;            // [64 rows][64 f]
    f16* Wt = (f16*)(smem + 8192);   // [64 n][64 k] = W2 transposed
    f16* T  = (f16*)(smem + 16384);  // [64 col][64 row]
#pragma unroll
    for (int nt = 0; nt < 4; ++nt) {
      float bv = bias[nt * 16 + lr];
#pragma unroll
      for (int r = 0; r < 4; ++r) {
        float h = acc[nt][r] + bv;
        h = h > 0.f ? h : 0.f;
        F[(16 * wv + 4 * lg + r) * 64 + nt * 16 + lr] = (f16)h;
      }
    }
    {
      int k = tid >> 2, n0 = (tid & 3) * 16;
      const float* wr = W2 + (size_t)k * 64 + n0;
#pragma unroll
      for (int i = 0; i < 16; ++i) Wt[(n0 + i) * 64 + k] = (f16)wr[i];
    }
    __syncthreads();
    f32x4 acc2[4] = {};
#pragma unroll
    for (int kk = 0; kk < 4; ++kk) {
      f16x4 a = *(const f16x4*)(F + (16 * wv + lr) * 64 + kk * 16 + 4 * lg);
#pragma unroll
      for (int nt = 0; nt < 4; ++nt) {
        f16x4 b = *(const f16x4*)(Wt + (nt * 16 + lr) * 64 + kk * 16 + 4 * lg);
        acc2[nt] = __builtin_amdgcn_mfma_f32_16x16x16f16(a, b, acc2[nt], 0, 0, 0);
      }
    }
    __syncthreads();
#pragma unroll
    for (int nt = 0; nt < 4; ++nt)
#pragma unroll
      for (int r = 0; r < 4; ++r)
        T[(nt * 16 + lr) * 64 + 16 * wv + 4 * lg + r] = (f16)acc2[nt][r];
    __syncthreads();
    {
      int col = tid >> 2, r0 = (tid & 3) * 16;
#pragma unroll
      for (int h = 0; h < 2; ++h)
        *(f32x4*)(S2t + (size_t)col * NN + m0 + r0 + 8 * h) =
            *(const f32x4*)(T + col * 64 + r0 + 8 * h);
    }
  } else {
    float wl[4];
#pragma unroll
    for (int r = 0; r < 4; ++r) wl[r] = wvec[m0 + 16 * wv + 4 * lg + r];
#pragma unroll
    for (int nt = 0; nt < 4; ++nt) {
      int c = nt * 16 + lr;
      float bv = bias[c];
#pragma unroll
      for (int r = 0; r < 4; ++r) {
        int row = m0 + 16 * wv + 4 * lg + r;
        out[(size_t)row * 64 + c] = (acc[nt][r] + bv) * wl[r];
      }
    }
    if (tid < 64) wout[m0 + tid] = wvec[m0 + tid];
  }
}

extern "C" void kernel_launch(void* const* d_in, const int* in_sizes, int n_in,
                              void* d_out, int out_size, void* d_ws, size_t ws_size,
                              hipStream_t stream) {
  (void)in_sizes; (void)n_in; (void)out_size; (void)ws_size;
  const float* x   = (const float*)d_in[0];
  const float* w   = (const float*)d_in[1];
  const float* adj = (const float*)d_in[2];
  const float* W1  = (const float*)d_in[3];
  const float* b1  = (const float*)d_in[4];
  const float* W2  = (const float*)d_in[5];
  const float* b2  = (const float*)d_in[6];

  float* out  = (float*)d_out;
  float* wout = out + (size_t)NN * FF;

  f16* S1t = (f16*)d_ws;                       // [64][16384] f16, 2 MB
  f16* S2t = (f16*)d_ws + (size_t)NN * FF;     // [64][16384] f16, 2 MB

  xw_kernel<<<NN / 64, 256, 0, stream>>>(x, W1, S1t);
  adj_pass<0><<<NN / 64, 256, 0, stream>>>(adj, S1t, b1, W2, nullptr, S2t,
                                           nullptr, nullptr);
  adj_pass<1><<<NN / 64, 256, 0, stream>>>(adj, S2t, b2, nullptr, w, nullptr,
                                           out, wout);
}

// Round 2
// 356.209 us; speedup vs baseline: 3.2336x; 3.2336x over previous
//
#include <hip/hip_runtime.h>
#include <cstdint>
#include <cstddef>

#define NN 16384
#define FF 64
#define BK 128
#define NT (NN / BK)            // 128 K-tiles
#define ABYTES (64 * BK * 4)    // 32 KB  A tile (fp32)
#define BBYTES (64 * BK * 2)    // 16 KB  B tile (f16)
#define BUFB (ABYTES + BBYTES)  // 48 KB per buffer, x3 = 144 KB LDS

typedef _Float16 f16;
typedef _Float16 f16x4 __attribute__((ext_vector_type(4)));
typedef float f32x4 __attribute__((ext_vector_type(4)));

// async global->LDS, 16B per lane. LDS dest = wave-uniform base + lane*16.
__device__ __forceinline__ void async_copy16(void* lds, const void* gsrc) {
  auto l = reinterpret_cast<__attribute__((address_space(3))) uint32_t*>(
      reinterpret_cast<uintptr_t>(lds));
  auto g = reinterpret_cast<const __attribute__((address_space(1))) uint32_t*>(
      reinterpret_cast<uintptr_t>(gsrc));
  __builtin_amdgcn_global_load_lds(g, l, 16, 0, 0);
}

// ---------------------------------------------------------------------------
// Kernel 0: S1t[f][i] = (x @ W1)[i][f] as f16  (transposed for B-frag loads)
// ---------------------------------------------------------------------------
__global__ __launch_bounds__(256, 1)
void xw_kernel(const float* __restrict__ x, const float* __restrict__ W1,
               f16* __restrict__ S1t) {
  __shared__ __align__(16) char smem[24576];
  f16* X  = (f16*)smem;            // [64 rows][64 k]
  f16* Wt = (f16*)(smem + 8192);   // [64 n][64 k]  (= W1 transposed)
  f16* T  = (f16*)(smem + 16384);  // [64 col][64 row]
  const int tid = threadIdx.x;
  const int wv = tid >> 6, lane = tid & 63;
  const int lr = lane & 15, lg = lane >> 4;
  const int m0 = blockIdx.x * 64;

  {
    int row = tid >> 2, c0 = (tid & 3) * 16;
    const float* xr = x + (size_t)(m0 + row) * FF + c0;
#pragma unroll
    for (int j = 0; j < 4; ++j) {
      f32x4 v = *(const f32x4*)(xr + 4 * j);
#pragma unroll
      for (int i = 0; i < 4; ++i) X[row * 64 + c0 + 4 * j + i] = (f16)v[i];
    }
    const float* wr = W1 + (size_t)row * FF + c0;   // row=k, c0=n0
#pragma unroll
    for (int i = 0; i < 16; ++i) Wt[(c0 + i) * 64 + row] = (f16)wr[i];
  }
  __syncthreads();

  f32x4 acc[4] = {};
#pragma unroll
  for (int kk = 0; kk < 4; ++kk) {
    f16x4 a = *(const f16x4*)(X + (16 * wv + lr) * 64 + kk * 16 + 4 * lg);
#pragma unroll
    for (int nt = 0; nt < 4; ++nt) {
      f16x4 b = *(const f16x4*)(Wt + (nt * 16 + lr) * 64 + kk * 16 + 4 * lg);
      acc[nt] = __builtin_amdgcn_mfma_f32_16x16x16f16(a, b, acc[nt], 0, 0, 0);
    }
  }
  __syncthreads();
#pragma unroll
  for (int nt = 0; nt < 4; ++nt)
#pragma unroll
    for (int r = 0; r < 4; ++r)
      T[(nt * 16 + lr) * 64 + 16 * wv + 4 * lg + r] = (f16)acc[nt][r];
  __syncthreads();
  {
    int col = tid >> 2, r0 = (tid & 3) * 16;
#pragma unroll
    for (int h = 0; h < 2; ++h)
      *(f32x4*)(S1t + (size_t)col * NN + m0 + r0 + 8 * h) =
          *(const f32x4*)(T + col * 64 + r0 + 8 * h);
  }
}

// ---------------------------------------------------------------------------
// Main pass: C = adj @ S (+bias, [relu, @W2 -> S2t] | [*w -> out])
// 256 blocks x 4 waves, BM=64, BK=128, 3-deep LDS pipeline, counted vmcnt.
// LDS XOR-swizzle (chunk16 ^= row&7) applied on BOTH the global source of
// global_load_lds (dest stays linear) and the ds_read side (rule #21).
// ---------------------------------------------------------------------------
template <int PASS>
__global__ __launch_bounds__(256, 1)
void adj_pass(const float* __restrict__ adj, const f16* __restrict__ Bt,
              const float* __restrict__ bias, const float* __restrict__ W2,
              const float* __restrict__ wvec, f16* __restrict__ S2t,
              float* __restrict__ out, float* __restrict__ wout) {
  __shared__ __align__(16) char smem[3 * BUFB];
  const int tid = threadIdx.x;
  const int wv = tid >> 6;
  const int lane = tid & 63;
  const int lr = lane & 15, lg = lane >> 4;
  const int m0 = blockIdx.x * 64;

  // Per-lane pre-swizzled global source pointers; advance BK each tile.
  const char* pA[8];
  const char* pB[4];
#pragma unroll
  for (int j = 0; j < 8; ++j) {
    int row = 16 * wv + 2 * j + (lane >> 5);            // A row this lane fills
    pA[j] = (const char*)(adj + (size_t)(m0 + row) * NN +
                          (((lane & 31) ^ (row & 7)) << 2));
  }
#pragma unroll
  for (int j = 0; j < 4; ++j) {
    int row = 16 * wv + 4 * j + (lane >> 4);            // B row this lane fills
    pB[j] = (const char*)(Bt + (size_t)row * NN +
                          (((lane & 15) ^ (row & 7)) << 3));
  }

  f32x4 acc[4] = {};
  const int sw = lr & 7;                     // row&7 for all our read rows
  const int rbA = (16 * wv + lr) * (BK * 4); // A row byte base

#define STAGE(buf_)                                                        \
  do {                                                                     \
    char* base_ = smem + (buf_) * BUFB;                                    \
    _Pragma("unroll") for (int j = 0; j < 8; ++j) {                        \
      async_copy16(base_ + (16 * wv + 2 * j) * (BK * 4), pA[j]);           \
      pA[j] += BK * 4;                                                     \
    }                                                                      \
    _Pragma("unroll") for (int j = 0; j < 4; ++j) {                        \
      async_copy16(base_ + ABYTES + (16 * wv + 4 * j) * (BK * 2), pB[j]);  \
      pB[j] += BK * 2;                                                     \
    }                                                                      \
  } while (0)

#define COMPUTE(buf_)                                                          \
  do {                                                                         \
    const char* Ab_ = smem + (buf_) * BUFB;                                    \
    const char* Bb_ = Ab_ + ABYTES;                                            \
    _Pragma("unroll") for (int kk = 0; kk < BK / 16; ++kk) {                   \
      f32x4 av = *(const f32x4*)(Ab_ + rbA + ((((kk << 2) | lg) ^ sw) << 4));  \
      f16x4 a = {(f16)av[0], (f16)av[1], (f16)av[2], (f16)av[3]};              \
      _Pragma("unroll") for (int nt = 0; nt < 4; ++nt) {                       \
        f16x4 b = *(const f16x4*)(Bb_ + (nt * 16 + lr) * (BK * 2) +            \
                                  ((((kk << 1) | (lg >> 1)) ^ sw) << 4) +      \
                                  ((lg & 1) << 3));                            \
        acc[nt] = __builtin_amdgcn_mfma_f32_16x16x16f16(a, b, acc[nt], 0, 0, 0); \
      }                                                                        \
    }                                                                          \
  } while (0)

  STAGE(0);
  STAGE(1);
  int cb = 0, sb = 2;
  for (int t = 0; t < NT - 2; ++t) {
    STAGE(sb);
    asm volatile("s_waitcnt vmcnt(24)" ::: "memory");  // tile t's 12 loads done
    __builtin_amdgcn_s_barrier();
    COMPUTE(cb);
    __builtin_amdgcn_s_barrier();                      // before re-staging buf
    cb = (cb == 2) ? 0 : cb + 1;
    sb = (sb == 2) ? 0 : sb + 1;
  }
  asm volatile("s_waitcnt vmcnt(12)" ::: "memory");
  __builtin_amdgcn_s_barrier();
  COMPUTE(cb);
  cb = (cb == 2) ? 0 : cb + 1;
  asm volatile("s_waitcnt vmcnt(0)" ::: "memory");
  __builtin_amdgcn_s_barrier();
  COMPUTE(cb);
  __syncthreads();   // before LDS reuse / exit
#undef STAGE
#undef COMPUTE

  if constexpr (PASS == 0) {
    // h = acc + b1; relu; F (f16) -> second MFMA vs W2 -> transpose-write S2t
    f16* F  = (f16*)smem;            // [64 rows][64 f]
    f16* Wt = (f16*)(smem + 8192);   // [64 n][64 k] = W2 transposed
    f16* T  = (f16*)(smem + 16384);  // [64 col][64 row]
#pragma unroll
    for (int nt = 0; nt < 4; ++nt) {
      float bv = bias[nt * 16 + lr];
#pragma unroll
      for (int r = 0; r < 4; ++r) {
        float h = acc[nt][r] + bv;
        h = h > 0.f ? h : 0.f;
        F[(16 * wv + 4 * lg + r) * 64 + nt * 16 + lr] = (f16)h;
      }
    }
    {
      int k = tid >> 2, n0 = (tid & 3) * 16;
      const float* wr = W2 + (size_t)k * 64 + n0;
#pragma unroll
      for (int i = 0; i < 16; ++i) Wt[(n0 + i) * 64 + k] = (f16)wr[i];
    }
    __syncthreads();
    f32x4 acc2[4] = {};
#pragma unroll
    for (int kk = 0; kk < 4; ++kk) {
      f16x4 a = *(const f16x4*)(F + (16 * wv + lr) * 64 + kk * 16 + 4 * lg);
#pragma unroll
      for (int nt = 0; nt < 4; ++nt) {
        f16x4 b = *(const f16x4*)(Wt + (nt * 16 + lr) * 64 + kk * 16 + 4 * lg);
        acc2[nt] = __builtin_amdgcn_mfma_f32_16x16x16f16(a, b, acc2[nt], 0, 0, 0);
      }
    }
    __syncthreads();
#pragma unroll
    for (int nt = 0; nt < 4; ++nt)
#pragma unroll
      for (int r = 0; r < 4; ++r)
        T[(nt * 16 + lr) * 64 + 16 * wv + 4 * lg + r] = (f16)acc2[nt][r];
    __syncthreads();
    {
      int col = tid >> 2, r0 = (tid & 3) * 16;
#pragma unroll
      for (int h = 0; h < 2; ++h)
        *(f32x4*)(S2t + (size_t)col * NN + m0 + r0 + 8 * h) =
            *(const f32x4*)(T + col * 64 + r0 + 8 * h);
    }
  } else {
    float wl[4];
#pragma unroll
    for (int r = 0; r < 4; ++r) wl[r] = wvec[m0 + 16 * wv + 4 * lg + r];
#pragma unroll
    for (int nt = 0; nt < 4; ++nt) {
      int c = nt * 16 + lr;
      float bv = bias[c];
#pragma unroll
      for (int r = 0; r < 4; ++r) {
        int row = m0 + 16 * wv + 4 * lg + r;
        out[(size_t)row * 64 + c] = (acc[nt][r] + bv) * wl[r];
      }
    }
    if (tid < 64) wout[m0 + tid] = wvec[m0 + tid];
  }
}

extern "C" void kernel_launch(void* const* d_in, const int* in_sizes, int n_in,
                              void* d_out, int out_size, void* d_ws, size_t ws_size,
                              hipStream_t stream) {
  (void)in_sizes; (void)n_in; (void)out_size; (void)ws_size;
  const float* x   = (const float*)d_in[0];
  const float* w   = (const float*)d_in[1];
  const float* adj = (const float*)d_in[2];
  const float* W1  = (const float*)d_in[3];
  const float* b1  = (const float*)d_in[4];
  const float* W2  = (const float*)d_in[5];
  const float* b2  = (const float*)d_in[6];

  float* out  = (float*)d_out;
  float* wout = out + (size_t)NN * FF;

  f16* S1t = (f16*)d_ws;                       // [64][16384] f16, 2 MB
  f16* S2t = (f16*)d_ws + (size_t)NN * FF;     // [64][16384] f16, 2 MB

  xw_kernel<<<NN / 64, 256, 0, stream>>>(x, W1, S1t);
  adj_pass<0><<<NN / 64, 256, 0, stream>>>(adj, S1t, b1, W2, nullptr, S2t,
                                           nullptr, nullptr);
  adj_pass<1><<<NN / 64, 256, 0, stream>>>(adj, S2t, b2, nullptr, w, nullptr,
                                           out, wout);
}